// Round 1
// 643.933 us; speedup vs baseline: 1.1202x; 1.1202x over previous
//
#include <hip/hip_runtime.h>
#include <math.h>

// Problem constants
// B=2048, T=24, N=231, D=512; conv images 16ch x 11 x 21 -> 32 x 5 x 10 -> 16 x 2 x 4
// Output layout (floats): weights[32768] | updated_cache[30277632] | new_predict[7569408] | new_timesnet_cache[16777216]
//
// Workspace layout (floats):
//   [0 .. 2*9312)          : per-path transposed weights + bn scale/shift (prep_kernel)
//       per path: w1t[144][32] | w2t[288][16] | sc1[32] | sh1[32] | pad[16]... sc2[16] | sh2[16]
//   [18624 .. 18624+262144): qbuf  (2048*16*8)
//   [..      +262144)      : kbuf

#define WPATH 9312

struct ProjParams {
  const float *W1, *b1, *g1, *be1, *m1, *v1;
  const float *W2, *b2, *g2, *be2, *m2, *v2;
};

// One-time weight transpose + BN scale/shift precompute. grid(2), block(256).
__global__ __launch_bounds__(256) void prep_kernel(
    ProjParams qp, ProjParams kp, float* __restrict__ wout)
{
  const int p   = blockIdx.x;
  const int tid = threadIdx.x;
  const ProjParams P = p ? kp : qp;
  float* wp = wout + p * WPATH;

  // W1 (OIHW 32x16x3x3) -> w1t[(ic*9+kh*3+kw)][oc], dst-ordered (coalesced write)
  for (int dst = tid; dst < 4608; dst += 256) {
    int rem = dst >> 5, oc = dst & 31;
    wp[dst] = P.W1[oc * 144 + rem];
  }
  // W2 (16x32x3x3) -> w2t[(ic*9+k)][oc]
  for (int dst = tid; dst < 4608; dst += 256) {
    int rem = dst >> 4, oc = dst & 15;
    wp[4608 + dst] = P.W2[oc * 288 + rem];
  }
  if (tid < 32) {
    float s = rsqrtf(P.v1[tid] + 1e-5f) * P.g1[tid];
    wp[9216 + tid] = s;
    wp[9248 + tid] = P.be1[tid] - P.m1[tid] * s;
  } else if (tid < 48) {
    int oc = tid - 32;
    float s = rsqrtf(P.v2[oc] + 1e-5f) * P.g2[oc];
    wp[9280 + oc] = s;
    wp[9296 + oc] = P.be2[oc] - P.m2[oc] * s;
  }
}

__global__ __launch_bounds__(256) void proj_kernel(
    const float* __restrict__ data0, const float* __restrict__ data2,
    const float* __restrict__ cache,
    const float* __restrict__ bike_start, const float* __restrict__ bike_end,
    const float* __restrict__ taxi_start, const float* __restrict__ taxi_end,
    ProjParams qp, ProjParams kp,
    const float* __restrict__ wt,
    float* __restrict__ qbuf, float* __restrict__ kbuf)
{
  const int b   = blockIdx.y;
  const int p   = blockIdx.x;      // 0 -> Q path, 1 -> K path
  const int tid = threadIdx.x;

  // LDS: 3696 + 4608 + 1600 = 9904 floats = 39.6 KB -> 4 blocks/CU
  __shared__ float xs[16 * 231];    // input image
  __shared__ float w1s[144 * 32];   // W1 transposed (copied pre-transposed, conflict-free)
  __shared__ float y1s[32 * 50];    // conv1 output (post relu+bn), [oc][oh*10+ow]

  const ProjParams P = p ? kp : qp;
  const float* wp = wt + p * WPATH;

  // ---- stage pre-transposed W1 into LDS: coalesced read, sequential write ----
  {
    const float4* wsrc4 = (const float4*)wp;
    float4* w1s4 = (float4*)w1s;
    for (int dst = tid; dst < 1152; dst += 256) w1s4[dst] = wsrc4[dst];
  }

  // ---- stage input image into LDS (vectorized) ----
  if (p == 0) {
    // q: ic = t*4 + f; f<2 from data0, f>=2 from data2; innermost global dim is f&1
    for (int e = tid; e < 1848; e += 256) {
      int pr = e / 231, n = e - pr * 231;
      int t = pr >> 1, half = pr & 1;
      const float2* src = (const float2*)(half ? data2 : data0);
      float2 v = src[(b * 24 + 20 + t) * 231 + n];
      int ic0 = t * 4 + half * 2;
      xs[ic0 * 231 + n]       = v.x;
      xs[(ic0 + 1) * 231 + n] = v.y;
    }
  } else {
    // k: ic = s*4 + f; s=0 from the four stacked arrays, s>=1 from cache[b][s][0][n][f]
    for (int e = tid; e < 924; e += 256) {
      int f = e / 231;
      const float* src = (f == 0) ? bike_start : (f == 1) ? bike_end
                       : (f == 2) ? taxi_start : taxi_end;
      xs[e] = src[b * 924 + (e - f * 231)];
    }
    for (int e = tid; e < 693; e += 256) {
      int s = e / 231 + 1, n = e - (s - 1) * 231;
      float4 v = ((const float4*)cache)[(b * 4 + s) * 924 + n];
      int ic0 = s * 4;
      xs[(ic0 + 0) * 231 + n] = v.x;
      xs[(ic0 + 1) * 231 + n] = v.y;
      xs[(ic0 + 2) * 231 + n] = v.z;
      xs[(ic0 + 3) * 231 + n] = v.w;
    }
  }
  __syncthreads();

  // ---- conv1: out 32oc x 5oh x 10ow; each of 80 threads does 4oc x 5ow ----
  if (tid < 80) {
    const int ocg = tid / 10, r = tid - ocg * 10;
    const int oh = r >> 1, owg = r & 1;
    const int oc0 = ocg * 4, ow0 = owg * 5;
    float acc[4][5];
#pragma unroll
    for (int i = 0; i < 4; ++i) {
      float bi = P.b1[oc0 + i];
#pragma unroll
      for (int j = 0; j < 5; ++j) acc[i][j] = bi;
    }
    for (int ic = 0; ic < 16; ++ic) {
      const float* xrow = &xs[ic * 231 + 2 * oh * 21 + 2 * ow0];
      const float* wrow = &w1s[ic * 9 * 32 + oc0];
#pragma unroll
      for (int kh = 0; kh < 3; ++kh) {
#pragma unroll
        for (int kw = 0; kw < 3; ++kw) {
          const float4 wv = *(const float4*)&wrow[(kh * 3 + kw) * 32];
          const float* xr = &xrow[kh * 21 + kw];
#pragma unroll
          for (int j = 0; j < 5; ++j) {
            float xv = xr[2 * j];
            acc[0][j] += wv.x * xv;
            acc[1][j] += wv.y * xv;
            acc[2][j] += wv.z * xv;
            acc[3][j] += wv.w * xv;
          }
        }
      }
    }
    const float* sc1 = wp + 9216;
    const float* sh1 = wp + 9248;
#pragma unroll
    for (int i = 0; i < 4; ++i) {
      float s = sc1[oc0 + i], h = sh1[oc0 + i];
#pragma unroll
      for (int j = 0; j < 5; ++j) {
        float v = fmaxf(acc[i][j], 0.0f);
        y1s[(oc0 + i) * 50 + oh * 10 + ow0 + j] = v * s + h;
      }
    }
  }
  __syncthreads();

  // ---- conv2: out 16oc x 2oh x 4ow; each of 32 threads does 2oc x 2ow ----
  // W2 read straight from the L1-resident pre-transposed global table (tiny phase).
  if (tid < 32) {
    const int ocg = tid >> 2, r = tid & 3;
    const int oh = r >> 1, owg = r & 1;
    const int oc0 = ocg * 2, ow0 = owg * 2;
    const float* w2t = wp + 4608;
    float acc[2][2];
#pragma unroll
    for (int i = 0; i < 2; ++i) {
      float bi = P.b2[oc0 + i];
      acc[i][0] = bi; acc[i][1] = bi;
    }
    for (int ic = 0; ic < 32; ++ic) {
      const float* yrow = &y1s[ic * 50 + 2 * oh * 10 + 2 * ow0];
      const float* wrow = &w2t[ic * 9 * 16 + oc0];
#pragma unroll
      for (int kh = 0; kh < 3; ++kh) {
#pragma unroll
        for (int kw = 0; kw < 3; ++kw) {
          const float2 wv = *(const float2*)&wrow[(kh * 3 + kw) * 16];
          const float* yr = &yrow[kh * 10 + kw];
#pragma unroll
          for (int j = 0; j < 2; ++j) {
            float yv = yr[2 * j];
            acc[0][j] += wv.x * yv;
            acc[1][j] += wv.y * yv;
          }
        }
      }
    }
    const float* sc2 = wp + 9280;
    const float* sh2 = wp + 9296;
    float* outp = p ? kbuf : qbuf;
#pragma unroll
    for (int i = 0; i < 2; ++i) {
      float s = sc2[oc0 + i], h = sh2[oc0 + i];
#pragma unroll
      for (int j = 0; j < 2; ++j) {
        float v = fmaxf(acc[i][j], 0.0f);
        outp[(b * 16 + oc0 + i) * 8 + oh * 4 + ow0 + j] = v * s + h;
      }
    }
  }
}

// Fused copy kernel: job by blockIdx.x range.
//  x in [0,11):  updated_cache[:,1:4] <- cache[:,1:4]        (2772 float4 / batch)
//  x in [11,15): new_predict + updated_cache[:,0] <- stack   (924 float4 / batch)
//  x in [15,23): new_timesnet_cache                          (2048 float4 / batch)
__global__ __launch_bounds__(256) void copy_kernel(
    const float4* __restrict__ cache4,
    const float* __restrict__ bike_start, const float* __restrict__ bike_end,
    const float* __restrict__ taxi_start, const float* __restrict__ taxi_end,
    const float4* __restrict__ io4, const float4* __restrict__ tc4,
    float4* __restrict__ out4)
{
  const int b   = blockIdx.y;
  const int x   = blockIdx.x;
  const int tid = threadIdx.x;
  float4* out_uc = out4 + 8192;      // 32768/4
  float4* out_np = out4 + 7577600;   // (32768+30277632)/4
  float4* out_tc = out4 + 9469952;   // (32768+30277632+7569408)/4

  if (x < 11) {
    int i = x * 256 + tid;
    if (i < 2772) {
      out_uc[b * 3696 + 924 + i] = cache4[b * 3696 + 924 + i];
    }
  } else if (x < 15) {
    int e = (x - 11) * 256 + tid;
    if (e < 924) {
      int idx = b * 924 + e;
      float4 v;
      v.x = bike_start[idx];
      v.y = bike_end[idx];
      v.z = taxi_start[idx];
      v.w = taxi_end[idx];
      out_np[idx] = v;               // new_predict[b][j][n][:]
      out_uc[b * 3696 + e] = v;      // updated_cache[b][0][j][n][:]
    }
  } else {
    int r = (x - 15) * 256 + tid;    // r in [0,2048)
    int s = r >> 9;
    float4 v;
    if (s == 0) {
      int t = (r >> 7) & 3;
      v = io4[(b * 24 + 20 + t) * 128 + (r & 127)];
    } else {
      v = tc4[b * 2048 + r];
    }
    out_tc[b * 2048 + r] = v;
  }
}

// scores (diagonal 4x4 blocks only) + softmax + mean -> weights.
// One 64-lane wave per batch; lane l = (a<<4)|(c<<2)|e.
__global__ __launch_bounds__(256) void score_kernel(
    const float* __restrict__ Qb, const float* __restrict__ Kb,
    float* __restrict__ wout)
{
  const int tid = threadIdx.x;
  const int b = blockIdx.x * 4 + (tid >> 6);
  const int l = tid & 63;
  const int a = (l >> 4) & 3, c = (l >> 2) & 3, e = l & 3;
  const float* qrow = Qb + (b * 16 + a * 4 + c) * 8;
  const float* krow = Kb + (b * 16 + a * 4 + e) * 8;
  float dot = 0.0f;
#pragma unroll
  for (int d = 0; d < 8; ++d) dot += qrow[d] * krow[d];
  float v = dot * 0.35355339059327373f;  // 1/sqrt(8)

  // softmax over e (lane bits 0-1)
  float m = fmaxf(v, __shfl_xor(v, 1));
  m = fmaxf(m, __shfl_xor(m, 2));
  float pe = expf(v - m);
  float ssum = pe + __shfl_xor(pe, 1);
  ssum += __shfl_xor(ssum, 2);
  float attn = pe / ssum;

  // mean over c (lane bits 2-3)
  float t = attn + __shfl_xor(attn, 4);
  t += __shfl_xor(t, 8);
  if (c == 0) wout[b * 16 + a * 4 + e] = 0.25f * t;
}

extern "C" void kernel_launch(void* const* d_in, const int* in_sizes, int n_in,
                              void* d_out, int out_size, void* d_ws, size_t ws_size,
                              hipStream_t stream) {
  const float* data0      = (const float*)d_in[0];
  const float* data2      = (const float*)d_in[1];
  const float* cache      = (const float*)d_in[2];
  const float* tcache     = (const float*)d_in[3];
  const float* bike_start = (const float*)d_in[4];
  const float* bike_end   = (const float*)d_in[5];
  const float* taxi_start = (const float*)d_in[6];
  const float* taxi_end   = (const float*)d_in[7];
  const float* iout       = (const float*)d_in[8];

  ProjParams qp = {
    (const float*)d_in[9],  (const float*)d_in[10], (const float*)d_in[11],
    (const float*)d_in[12], (const float*)d_in[13], (const float*)d_in[14],
    (const float*)d_in[15], (const float*)d_in[16], (const float*)d_in[17],
    (const float*)d_in[18], (const float*)d_in[19], (const float*)d_in[20]
  };
  ProjParams kp = {
    (const float*)d_in[21], (const float*)d_in[22], (const float*)d_in[23],
    (const float*)d_in[24], (const float*)d_in[25], (const float*)d_in[26],
    (const float*)d_in[27], (const float*)d_in[28], (const float*)d_in[29],
    (const float*)d_in[30], (const float*)d_in[31], (const float*)d_in[32]
  };

  float* wt   = (float*)d_ws;              // 2*9312 floats
  float* qbuf = wt + 2 * WPATH;            // 2048*16*8 floats (16B-aligned: 18624*4 B)
  float* kbuf = qbuf + 2048 * 16 * 8;
  float* out  = (float*)d_out;

  hipLaunchKernelGGL(prep_kernel, dim3(2), dim3(256), 0, stream, qp, kp, wt);
  hipLaunchKernelGGL(proj_kernel, dim3(2, 2048), dim3(256), 0, stream,
                     data0, data2, cache, bike_start, bike_end, taxi_start,
                     taxi_end, qp, kp, wt, qbuf, kbuf);
  hipLaunchKernelGGL(copy_kernel, dim3(23, 2048), dim3(256), 0, stream,
                     (const float4*)cache, bike_start, bike_end, taxi_start,
                     taxi_end, (const float4*)iout, (const float4*)tcache,
                     (float4*)out);
  hipLaunchKernelGGL(score_kernel, dim3(512), dim3(256), 0, stream,
                     qbuf, kbuf, out);
}